// Round 1
// baseline (1258.969 us; speedup 1.0000x reference)
//
#include <hip/hip_runtime.h>
#include <hip/hip_bf16.h>

#define Nn 100000
#define Ee 1600000
#define Hh 128
#define Gg 1000
#define EPSb 1e-5f

#define SCAN_CHUNK 1024
#define NB_SCAN 98          // ceil(100000/1024)
#define AGG_BLOCKS 1024
#define GEMM_BLOCKS 782     // ceil(100000/128)

// ---------------- graph preprocessing ----------------

__global__ void k_init(int* __restrict__ deg, int* __restrict__ cursor,
                       float* __restrict__ colsum) {
    int i = blockIdx.x * blockDim.x + threadIdx.x;
    if (i < Nn) { deg[i] = 1; cursor[i] = 0; }
    if (i < 256) colsum[i] = 0.f;
}

__global__ void k_deg(const int* __restrict__ dst, int* __restrict__ deg) {
    int i = blockIdx.x * blockDim.x + threadIdx.x;
    if (i < Ee) atomicAdd(&deg[dst[i]], 1);
}

__global__ void k_dinv(const int* __restrict__ deg, float* __restrict__ dinv) {
    int i = blockIdx.x * blockDim.x + threadIdx.x;
    if (i < Nn) dinv[i] = rsqrtf((float)deg[i]);
}

__global__ void k_scan1(const int* __restrict__ deg, int* __restrict__ bsum) {
    __shared__ int ls[256];
    int t = threadIdx.x;
    int base = blockIdx.x * SCAN_CHUNK + t * 4;
    int s = 0;
#pragma unroll
    for (int j = 0; j < 4; ++j) { int i = base + j; if (i < Nn) s += deg[i]; }
    ls[t] = s;
    __syncthreads();
    for (int off = 128; off; off >>= 1) {
        if (t < off) ls[t] += ls[t + off];
        __syncthreads();
    }
    if (t == 0) bsum[blockIdx.x] = ls[0];
}

__global__ void k_scan2(int* __restrict__ bsum, int nb) {
    int acc = 0;
    for (int b = 0; b < nb; ++b) { int v = bsum[b]; bsum[b] = acc; acc += v; }
}

__global__ void k_scan3(const int* __restrict__ deg, const int* __restrict__ bsum,
                        int* __restrict__ offs) {
    __shared__ int ls[256];
    int t = threadIdx.x;
    int base = blockIdx.x * SCAN_CHUNK + t * 4;
    int d[4]; int s = 0;
#pragma unroll
    for (int j = 0; j < 4; ++j) {
        int i = base + j;
        d[j] = (i < Nn) ? deg[i] : 0;
        s += d[j];
    }
    ls[t] = s;
    __syncthreads();
    for (int off = 1; off < 256; off <<= 1) {
        int u = (t >= off) ? ls[t - off] : 0;
        __syncthreads();
        ls[t] += u;
        __syncthreads();
    }
    int run = bsum[blockIdx.x] + ls[t] - s;   // exclusive prefix for this thread
#pragma unroll
    for (int j = 0; j < 4; ++j) {
        int i = base + j;
        if (i < Nn) offs[i] = run;
        run += d[j];
    }
    if (blockIdx.x == 0 && t == 0) offs[Nn] = Ee + Nn;
}

__global__ void k_fill(const int* __restrict__ src, const int* __restrict__ dst,
                       const int* __restrict__ offs, int* __restrict__ cursor,
                       const float* __restrict__ dinv,
                       int* __restrict__ adj_s, float* __restrict__ adj_w) {
    int i = blockIdx.x * blockDim.x + threadIdx.x;
    if (i >= Ee + Nn) return;
    int s, d;
    if (i < Ee) { s = src[i]; d = dst[i]; }
    else        { s = d = i - Ee; }
    int pos = offs[d] + atomicAdd(&cursor[d], 1);
    adj_s[pos] = s;
    adj_w[pos] = dinv[s] * dinv[d];
}

// ---------------- GEMM: out = act(in) @ W  (act = BN+ReLU of prev layer) ----

__global__ __launch_bounds__(256) void k_gemm(
    const float* __restrict__ in, const float* __restrict__ W,
    const float* __restrict__ scale, const float* __restrict__ shift,
    float* __restrict__ out, int use_bn) {
    __shared__ float xT[32][128];   // xT[k][r]
    __shared__ float Ws[32][128];   // Ws[k][c]
    int tid = threadIdx.x;
    int rowBase = blockIdx.x * 128;
    int tr = ((tid >> 4) & 15) * 8;
    int tc = (tid & 15) * 8;
    float acc[8][8] = {};

    for (int kc = 0; kc < 128; kc += 32) {
        {   // stage x chunk (transposed)
            int r = tid & 127;
            int ch = (tid >> 7) * 16;
            int gr = rowBase + r;
            int grc = gr < Nn ? gr : Nn - 1;
            const float* srcp = in + (size_t)grc * 128 + kc + ch;
#pragma unroll
            for (int j4 = 0; j4 < 16; j4 += 4) {
                float4 v = *(const float4*)(srcp + j4);
                if (use_bn) {
                    int c = kc + ch + j4;
                    float4 s4 = *(const float4*)(scale + c);
                    float4 h4 = *(const float4*)(shift + c);
                    v.x = fmaxf(fmaf(v.x, s4.x, h4.x), 0.f);
                    v.y = fmaxf(fmaf(v.y, s4.y, h4.y), 0.f);
                    v.z = fmaxf(fmaf(v.z, s4.z, h4.z), 0.f);
                    v.w = fmaxf(fmaf(v.w, s4.w, h4.w), 0.f);
                }
                xT[ch + j4 + 0][r] = v.x;
                xT[ch + j4 + 1][r] = v.y;
                xT[ch + j4 + 2][r] = v.z;
                xT[ch + j4 + 3][r] = v.w;
            }
        }
        {   // stage W chunk
            int k_ = tid & 31;
            int cg = (tid >> 5) * 16;
            const float* srcp = W + (size_t)(kc + k_) * 128 + cg;
#pragma unroll
            for (int j4 = 0; j4 < 16; j4 += 4)
                *(float4*)&Ws[k_][cg + j4] = *(const float4*)(srcp + j4);
        }
        __syncthreads();
#pragma unroll
        for (int k = 0; k < 32; ++k) {
            float4 a0 = *(const float4*)&xT[k][tr];
            float4 a1 = *(const float4*)&xT[k][tr + 4];
            float4 b0 = *(const float4*)&Ws[k][tc];
            float4 b1 = *(const float4*)&Ws[k][tc + 4];
            float a[8] = {a0.x, a0.y, a0.z, a0.w, a1.x, a1.y, a1.z, a1.w};
            float b[8] = {b0.x, b0.y, b0.z, b0.w, b1.x, b1.y, b1.z, b1.w};
#pragma unroll
            for (int i = 0; i < 8; ++i)
#pragma unroll
                for (int j = 0; j < 8; ++j)
                    acc[i][j] = fmaf(a[i], b[j], acc[i][j]);
        }
        __syncthreads();
    }
#pragma unroll
    for (int i = 0; i < 8; ++i) {
        int gr = rowBase + tr + i;
        if (gr < Nn) {
            float4 o0 = make_float4(acc[i][0], acc[i][1], acc[i][2], acc[i][3]);
            float4 o1 = make_float4(acc[i][4], acc[i][5], acc[i][6], acc[i][7]);
            *(float4*)(out + (size_t)gr * 128 + tc) = o0;
            *(float4*)(out + (size_t)gr * 128 + tc + 4) = o1;
        }
    }
}

// ---------------- aggregation: agg[d] = sum_e w*h[src] + bias; BN partials ----

__global__ __launch_bounds__(256) void k_agg(
    const float* __restrict__ h, const int* __restrict__ offs,
    const int* __restrict__ adj_s, const float* __restrict__ adj_w,
    const float* __restrict__ bias, float* __restrict__ agg,
    float* __restrict__ colsum) {
    __shared__ float ls[256];
    int tid = threadIdx.x;
    ls[tid] = 0.f;
    __syncthreads();
    int lane = tid & 63;
    int gw = blockIdx.x * 4 + (tid >> 6);
    int nw = gridDim.x * 4;
    int c0 = lane * 2;
    float b0 = bias[c0], b1 = bias[c0 + 1];
    float ps0 = 0.f, pq0 = 0.f, ps1 = 0.f, pq1 = 0.f;
    for (int d = gw; d < Nn; d += nw) {
        int beg = offs[d], end = offs[d + 1];
        float a0 = 0.f, a1 = 0.f;
        for (int i = beg; i < end; ++i) {
            int s = adj_s[i];
            float w = adj_w[i];
            const float2 hv = *(const float2*)(h + (size_t)s * 128 + c0);
            a0 = fmaf(w, hv.x, a0);
            a1 = fmaf(w, hv.y, a1);
        }
        a0 += b0; a1 += b1;
        *(float2*)(agg + (size_t)d * 128 + c0) = make_float2(a0, a1);
        ps0 += a0; pq0 += a0 * a0;
        ps1 += a1; pq1 += a1 * a1;
    }
    atomicAdd(&ls[c0], ps0);
    atomicAdd(&ls[c0 + 1], ps1);
    atomicAdd(&ls[128 + c0], pq0);
    atomicAdd(&ls[128 + c0 + 1], pq1);
    __syncthreads();
    atomicAdd(&colsum[tid], ls[tid]);
}

// ---------------- BN finalize: scale/shift, re-zero accumulators ----------

__global__ void k_bnfinal(float* __restrict__ colsum,
                          const float* __restrict__ g, const float* __restrict__ be,
                          float* __restrict__ scale, float* __restrict__ shift) {
    int t = threadIdx.x;  // 128
    float s = colsum[t], q = colsum[128 + t];
    float m = s * (1.0f / Nn);
    float var = q * (1.0f / Nn) - m * m;
    float istd = rsqrtf(var + EPSb);
    float sc = istd * g[t];
    scale[t] = sc;
    shift[t] = fmaf(-m, sc, be[t]);
    colsum[t] = 0.f;
    colsum[128 + t] = 0.f;
}

// ---------------- pool + linear ------------------------------------------

__global__ __launch_bounds__(256) void k_pool(
    const float* __restrict__ agg, const int* __restrict__ batch,
    const float* __restrict__ scale, const float* __restrict__ shift,
    const float* __restrict__ Wl, const float* __restrict__ bl,
    float* __restrict__ out) {
    int lane = threadIdx.x & 63;
    int g = (blockIdx.x * blockDim.x + threadIdx.x) >> 6;
    if (g >= Gg) return;
    int lo = 0, hi = Nn;
    while (lo < hi) { int mid = (lo + hi) >> 1; if (batch[mid] < g) lo = mid + 1; else hi = mid; }
    int beg = lo;
    hi = Nn;
    while (lo < hi) { int mid = (lo + hi) >> 1; if (batch[mid] < g + 1) lo = mid + 1; else hi = mid; }
    int end = lo;
    int c0 = lane * 2;
    float sc0 = scale[c0], sh0 = shift[c0];
    float sc1 = scale[c0 + 1], sh1 = shift[c0 + 1];
    float s0 = 0.f, s1 = 0.f;
    for (int n = beg; n < end; ++n) {
        float2 v = *(const float2*)(agg + (size_t)n * 128 + c0);
        s0 += fmaxf(fmaf(v.x, sc0, sh0), 0.f);
        s1 += fmaxf(fmaf(v.y, sc1, sh1), 0.f);
    }
    float inv = 1.0f / fmaxf((float)(end - beg), 1.0f);
    float part = (s0 * inv) * Wl[c0] + (s1 * inv) * Wl[c0 + 1];
#pragma unroll
    for (int off = 32; off; off >>= 1) part += __shfl_down(part, off);
    if (lane == 0) out[g] = part + bl[0];
}

// ---------------- launch --------------------------------------------------

extern "C" void kernel_launch(void* const* d_in, const int* in_sizes, int n_in,
                              void* d_out, int out_size, void* d_ws, size_t ws_size,
                              hipStream_t stream) {
    const float* x   = (const float*)d_in[0];
    const int*   ei  = (const int*)d_in[1];
    const int*   src = ei;
    const int*   dst = ei + Ee;
    const int*   bat = (const int*)d_in[2];
    const float* W1 = (const float*)d_in[3];
    const float* b1 = (const float*)d_in[4];
    const float* g1 = (const float*)d_in[5];
    const float* be1 = (const float*)d_in[6];
    const float* W2 = (const float*)d_in[7];
    const float* b2 = (const float*)d_in[8];
    const float* g2 = (const float*)d_in[9];
    const float* be2 = (const float*)d_in[10];
    const float* W3 = (const float*)d_in[11];
    const float* b3 = (const float*)d_in[12];
    const float* g3 = (const float*)d_in[13];
    const float* be3 = (const float*)d_in[14];
    const float* Wl = (const float*)d_in[15];
    const float* bl = (const float*)d_in[16];
    float* out = (float*)d_out;

    char* w = (char*)d_ws;
    auto alloc = [&](size_t bytes) {
        void* p = (void*)w;
        w += (bytes + 255) & ~(size_t)255;
        return p;
    };
    int*   deg    = (int*)alloc((size_t)Nn * 4);
    int*   cursor = (int*)alloc((size_t)Nn * 4);
    int*   offs   = (int*)alloc((size_t)(Nn + 1) * 4);
    int*   bsum   = (int*)alloc(256 * 4);
    float* dinv   = (float*)alloc((size_t)Nn * 4);
    float* colsum = (float*)alloc(256 * 4);
    float* scale  = (float*)alloc(128 * 4);
    float* shift  = (float*)alloc(128 * 4);
    int*   adj_s  = (int*)alloc((size_t)(Ee + Nn) * 4);
    float* adj_w  = (float*)alloc((size_t)(Ee + Nn) * 4);
    float* tmp    = (float*)alloc((size_t)Nn * 128 * 4);
    float* agg    = (float*)alloc((size_t)Nn * 128 * 4);

    // graph preprocessing
    k_init<<<(Nn + 255) / 256, 256, 0, stream>>>(deg, cursor, colsum);
    k_deg<<<(Ee + 255) / 256, 256, 0, stream>>>(dst, deg);
    k_dinv<<<(Nn + 255) / 256, 256, 0, stream>>>(deg, dinv);
    k_scan1<<<NB_SCAN, 256, 0, stream>>>(deg, bsum);
    k_scan2<<<1, 1, 0, stream>>>(bsum, NB_SCAN);
    k_scan3<<<NB_SCAN, 256, 0, stream>>>(deg, bsum, offs);
    k_fill<<<(Ee + Nn + 255) / 256, 256, 0, stream>>>(src, dst, offs, cursor, dinv,
                                                      adj_s, adj_w);
    // layer 1
    k_gemm<<<GEMM_BLOCKS, 256, 0, stream>>>(x, W1, scale, shift, tmp, 0);
    k_agg<<<AGG_BLOCKS, 256, 0, stream>>>(tmp, offs, adj_s, adj_w, b1, agg, colsum);
    k_bnfinal<<<1, 128, 0, stream>>>(colsum, g1, be1, scale, shift);
    // layer 2
    k_gemm<<<GEMM_BLOCKS, 256, 0, stream>>>(agg, W2, scale, shift, tmp, 1);
    k_agg<<<AGG_BLOCKS, 256, 0, stream>>>(tmp, offs, adj_s, adj_w, b2, agg, colsum);
    k_bnfinal<<<1, 128, 0, stream>>>(colsum, g2, be2, scale, shift);
    // layer 3
    k_gemm<<<GEMM_BLOCKS, 256, 0, stream>>>(agg, W3, scale, shift, tmp, 1);
    k_agg<<<AGG_BLOCKS, 256, 0, stream>>>(tmp, offs, adj_s, adj_w, b3, agg, colsum);
    k_bnfinal<<<1, 128, 0, stream>>>(colsum, g3, be3, scale, shift);
    // pool + linear
    k_pool<<<(Gg * 64 + 255) / 256, 256, 0, stream>>>(agg, bat, scale, shift, Wl, bl, out);
}

// Round 2
// 751.529 us; speedup vs baseline: 1.6752x; 1.6752x over previous
//
#include <hip/hip_runtime.h>
#include <hip/hip_bf16.h>

#define Nn 100000
#define Ee 1600000
#define Hh 128
#define Gg 1000
#define EPSb 1e-5f

#define SCAN_CHUNK 1024
#define NB_SCAN 98          // ceil(100000/1024)
#define AGG_BLOCKS 2048
#define GEMM_BLOCKS 782     // ceil(100000/128)

typedef unsigned int uint;

// round-to-nearest-even f32 -> bf16 (as low 16 bits of return)
static __device__ __forceinline__ uint bf16rne(float f) {
    uint u = __float_as_uint(f);
    return (u + 0x7fffu + ((u >> 16) & 1u)) >> 16;
}

// ---------------- graph preprocessing ----------------

__global__ void k_init(int* __restrict__ deg, int* __restrict__ cursor,
                       float* __restrict__ colsum) {
    int i = blockIdx.x * blockDim.x + threadIdx.x;
    if (i < Nn) { deg[i] = 1; cursor[i] = 0; }
    if (i < 256) colsum[i] = 0.f;
}

__global__ void k_deg(const int* __restrict__ dst, int* __restrict__ deg) {
    int i = blockIdx.x * blockDim.x + threadIdx.x;
    if (i < Ee) atomicAdd(&deg[dst[i]], 1);
}

__global__ void k_dinv(const int* __restrict__ deg, float* __restrict__ dinv) {
    int i = blockIdx.x * blockDim.x + threadIdx.x;
    if (i < Nn) dinv[i] = rsqrtf((float)deg[i]);
}

__global__ void k_scan1(const int* __restrict__ deg, int* __restrict__ bsum) {
    __shared__ int ls[256];
    int t = threadIdx.x;
    int base = blockIdx.x * SCAN_CHUNK + t * 4;
    int s = 0;
#pragma unroll
    for (int j = 0; j < 4; ++j) { int i = base + j; if (i < Nn) s += deg[i]; }
    ls[t] = s;
    __syncthreads();
    for (int off = 128; off; off >>= 1) {
        if (t < off) ls[t] += ls[t + off];
        __syncthreads();
    }
    if (t == 0) bsum[blockIdx.x] = ls[0];
}

__global__ void k_scan2(int* __restrict__ bsum, int nb) {
    int acc = 0;
    for (int b = 0; b < nb; ++b) { int v = bsum[b]; bsum[b] = acc; acc += v; }
}

__global__ void k_scan3(const int* __restrict__ deg, const int* __restrict__ bsum,
                        int* __restrict__ offs) {
    __shared__ int ls[256];
    int t = threadIdx.x;
    int base = blockIdx.x * SCAN_CHUNK + t * 4;
    int d[4]; int s = 0;
#pragma unroll
    for (int j = 0; j < 4; ++j) {
        int i = base + j;
        d[j] = (i < Nn) ? deg[i] : 0;
        s += d[j];
    }
    ls[t] = s;
    __syncthreads();
    for (int off = 1; off < 256; off <<= 1) {
        int u = (t >= off) ? ls[t - off] : 0;
        __syncthreads();
        ls[t] += u;
        __syncthreads();
    }
    int run = bsum[blockIdx.x] + ls[t] - s;   // exclusive prefix for this thread
#pragma unroll
    for (int j = 0; j < 4; ++j) {
        int i = base + j;
        if (i < Nn) offs[i] = run;
        run += d[j];
    }
    if (blockIdx.x == 0 && t == 0) offs[Nn] = Ee + Nn;
}

__global__ void k_fill(const int* __restrict__ src, const int* __restrict__ dst,
                       const int* __restrict__ offs, int* __restrict__ cursor,
                       const float* __restrict__ dinv,
                       int2* __restrict__ adj) {
    int i = blockIdx.x * blockDim.x + threadIdx.x;
    if (i >= Ee + Nn) return;
    int s, d;
    if (i < Ee) { s = src[i]; d = dst[i]; }
    else        { s = d = i - Ee; }
    int pos = offs[d] + atomicAdd(&cursor[d], 1);
    adj[pos] = make_int2(s, __float_as_int(dinv[s] * dinv[d]));
}

// ---------------- GEMM: out(bf16) = act(in) @ W  (act = BN+ReLU prev) ----

__global__ __launch_bounds__(256) void k_gemm(
    const float* __restrict__ in, const float* __restrict__ W,
    const float* __restrict__ scale, const float* __restrict__ shift,
    uint* __restrict__ outb, int use_bn) {
    __shared__ float xT[32][128];   // xT[k][r]
    __shared__ float Ws[32][128];   // Ws[k][c]
    int tid = threadIdx.x;
    int rowBase = blockIdx.x * 128;
    int tr = ((tid >> 4) & 15) * 8;
    int tc = (tid & 15) * 8;
    float acc[8][8] = {};

    for (int kc = 0; kc < 128; kc += 32) {
        {   // stage x chunk (transposed)
            int r = tid & 127;
            int ch = (tid >> 7) * 16;
            int gr = rowBase + r;
            int grc = gr < Nn ? gr : Nn - 1;
            const float* srcp = in + (size_t)grc * 128 + kc + ch;
#pragma unroll
            for (int j4 = 0; j4 < 16; j4 += 4) {
                float4 v = *(const float4*)(srcp + j4);
                if (use_bn) {
                    int c = kc + ch + j4;
                    float4 s4 = *(const float4*)(scale + c);
                    float4 h4 = *(const float4*)(shift + c);
                    v.x = fmaxf(fmaf(v.x, s4.x, h4.x), 0.f);
                    v.y = fmaxf(fmaf(v.y, s4.y, h4.y), 0.f);
                    v.z = fmaxf(fmaf(v.z, s4.z, h4.z), 0.f);
                    v.w = fmaxf(fmaf(v.w, s4.w, h4.w), 0.f);
                }
                xT[ch + j4 + 0][r] = v.x;
                xT[ch + j4 + 1][r] = v.y;
                xT[ch + j4 + 2][r] = v.z;
                xT[ch + j4 + 3][r] = v.w;
            }
        }
        {   // stage W chunk
            int k_ = tid & 31;
            int cg = (tid >> 5) * 16;
            const float* srcp = W + (size_t)(kc + k_) * 128 + cg;
#pragma unroll
            for (int j4 = 0; j4 < 16; j4 += 4)
                *(float4*)&Ws[k_][cg + j4] = *(const float4*)(srcp + j4);
        }
        __syncthreads();
#pragma unroll
        for (int k = 0; k < 32; ++k) {
            float4 a0 = *(const float4*)&xT[k][tr];
            float4 a1 = *(const float4*)&xT[k][tr + 4];
            float4 b0 = *(const float4*)&Ws[k][tc];
            float4 b1 = *(const float4*)&Ws[k][tc + 4];
            float a[8] = {a0.x, a0.y, a0.z, a0.w, a1.x, a1.y, a1.z, a1.w};
            float b[8] = {b0.x, b0.y, b0.z, b0.w, b1.x, b1.y, b1.z, b1.w};
#pragma unroll
            for (int i = 0; i < 8; ++i)
#pragma unroll
                for (int j = 0; j < 8; ++j)
                    acc[i][j] = fmaf(a[i], b[j], acc[i][j]);
        }
        __syncthreads();
    }
#pragma unroll
    for (int i = 0; i < 8; ++i) {
        int gr = rowBase + tr + i;
        if (gr < Nn) {
            uint4 o;
            o.x = bf16rne(acc[i][0]) | (bf16rne(acc[i][1]) << 16);
            o.y = bf16rne(acc[i][2]) | (bf16rne(acc[i][3]) << 16);
            o.z = bf16rne(acc[i][4]) | (bf16rne(acc[i][5]) << 16);
            o.w = bf16rne(acc[i][6]) | (bf16rne(acc[i][7]) << 16);
            *(uint4*)(outb + (size_t)gr * 64 + (tc >> 1)) = o;
        }
    }
}

// ------- aggregation: agg[d] = sum_e w*h[src] + bias; BN partials -------
// h is bf16-packed: row stride 64 uints, uint j holds cols 2j (lo), 2j+1 (hi)

__global__ __launch_bounds__(256) void k_agg(
    const uint* __restrict__ h32, const int* __restrict__ offs,
    const int2* __restrict__ adj,
    const float* __restrict__ bias, float* __restrict__ agg,
    float* __restrict__ colsum) {
    __shared__ float ls[256];
    int tid = threadIdx.x;
    ls[tid] = 0.f;
    __syncthreads();
    int lane = tid & 63;
    int gw = blockIdx.x * 4 + (tid >> 6);
    int nw = gridDim.x * 4;
    int c0 = lane * 2;
    float b0 = bias[c0], b1 = bias[c0 + 1];
    float ps0 = 0.f, pq0 = 0.f, ps1 = 0.f, pq1 = 0.f;
    for (int d = gw; d < Nn; d += nw) {
        int beg = offs[d], end = offs[d + 1];
        float a0 = 0.f, a1 = 0.f;
        int i = beg;
        for (; i + 8 <= end; i += 8) {
            int2 e[8];
#pragma unroll
            for (int j = 0; j < 8; ++j) e[j] = adj[i + j];
            uint hv[8];
#pragma unroll
            for (int j = 0; j < 8; ++j)
                hv[j] = h32[(size_t)e[j].x * 64 + lane];
#pragma unroll
            for (int j = 0; j < 8; ++j) {
                float w = __int_as_float(e[j].y);
                a0 = fmaf(w, __uint_as_float(hv[j] << 16), a0);
                a1 = fmaf(w, __uint_as_float(hv[j] & 0xffff0000u), a1);
            }
        }
        for (; i < end; ++i) {
            int2 e = adj[i];
            uint hv = h32[(size_t)e.x * 64 + lane];
            float w = __int_as_float(e.y);
            a0 = fmaf(w, __uint_as_float(hv << 16), a0);
            a1 = fmaf(w, __uint_as_float(hv & 0xffff0000u), a1);
        }
        a0 += b0; a1 += b1;
        *(float2*)(agg + (size_t)d * 128 + c0) = make_float2(a0, a1);
        ps0 += a0; pq0 += a0 * a0;
        ps1 += a1; pq1 += a1 * a1;
    }
    atomicAdd(&ls[c0], ps0);
    atomicAdd(&ls[c0 + 1], ps1);
    atomicAdd(&ls[128 + c0], pq0);
    atomicAdd(&ls[128 + c0 + 1], pq1);
    __syncthreads();
    atomicAdd(&colsum[tid], ls[tid]);
}

// ---------------- BN finalize: scale/shift, re-zero accumulators ----------

__global__ void k_bnfinal(float* __restrict__ colsum,
                          const float* __restrict__ g, const float* __restrict__ be,
                          float* __restrict__ scale, float* __restrict__ shift) {
    int t = threadIdx.x;  // 128
    float s = colsum[t], q = colsum[128 + t];
    float m = s * (1.0f / Nn);
    float var = q * (1.0f / Nn) - m * m;
    float istd = rsqrtf(var + EPSb);
    float sc = istd * g[t];
    scale[t] = sc;
    shift[t] = fmaf(-m, sc, be[t]);
    colsum[t] = 0.f;
    colsum[128 + t] = 0.f;
}

// ---------------- pool + linear ------------------------------------------

__global__ __launch_bounds__(256) void k_pool(
    const float* __restrict__ agg, const int* __restrict__ batch,
    const float* __restrict__ scale, const float* __restrict__ shift,
    const float* __restrict__ Wl, const float* __restrict__ bl,
    float* __restrict__ out) {
    int lane = threadIdx.x & 63;
    int g = (blockIdx.x * blockDim.x + threadIdx.x) >> 6;
    if (g >= Gg) return;
    int lo = 0, hi = Nn;
    while (lo < hi) { int mid = (lo + hi) >> 1; if (batch[mid] < g) lo = mid + 1; else hi = mid; }
    int beg = lo;
    hi = Nn;
    while (lo < hi) { int mid = (lo + hi) >> 1; if (batch[mid] < g + 1) lo = mid + 1; else hi = mid; }
    int end = lo;
    int c0 = lane * 2;
    float sc0 = scale[c0], sh0 = shift[c0];
    float sc1 = scale[c0 + 1], sh1 = shift[c0 + 1];
    float s0 = 0.f, s1 = 0.f;
    for (int n = beg; n < end; ++n) {
        float2 v = *(const float2*)(agg + (size_t)n * 128 + c0);
        s0 += fmaxf(fmaf(v.x, sc0, sh0), 0.f);
        s1 += fmaxf(fmaf(v.y, sc1, sh1), 0.f);
    }
    float inv = 1.0f / fmaxf((float)(end - beg), 1.0f);
    float part = (s0 * inv) * Wl[c0] + (s1 * inv) * Wl[c0 + 1];
#pragma unroll
    for (int off = 32; off; off >>= 1) part += __shfl_down(part, off);
    if (lane == 0) out[g] = part + bl[0];
}

// ---------------- launch --------------------------------------------------

extern "C" void kernel_launch(void* const* d_in, const int* in_sizes, int n_in,
                              void* d_out, int out_size, void* d_ws, size_t ws_size,
                              hipStream_t stream) {
    const float* x   = (const float*)d_in[0];
    const int*   ei  = (const int*)d_in[1];
    const int*   src = ei;
    const int*   dst = ei + Ee;
    const int*   bat = (const int*)d_in[2];
    const float* W1 = (const float*)d_in[3];
    const float* b1 = (const float*)d_in[4];
    const float* g1 = (const float*)d_in[5];
    const float* be1 = (const float*)d_in[6];
    const float* W2 = (const float*)d_in[7];
    const float* b2 = (const float*)d_in[8];
    const float* g2 = (const float*)d_in[9];
    const float* be2 = (const float*)d_in[10];
    const float* W3 = (const float*)d_in[11];
    const float* b3 = (const float*)d_in[12];
    const float* g3 = (const float*)d_in[13];
    const float* be3 = (const float*)d_in[14];
    const float* Wl = (const float*)d_in[15];
    const float* bl = (const float*)d_in[16];
    float* out = (float*)d_out;

    char* w = (char*)d_ws;
    auto alloc = [&](size_t bytes) {
        void* p = (void*)w;
        w += (bytes + 255) & ~(size_t)255;
        return p;
    };
    int*   deg    = (int*)alloc((size_t)Nn * 4);
    int*   cursor = (int*)alloc((size_t)Nn * 4);
    int*   offs   = (int*)alloc((size_t)(Nn + 1) * 4);
    int*   bsum   = (int*)alloc(256 * 4);
    float* dinv   = (float*)alloc((size_t)Nn * 4);
    float* colsum = (float*)alloc(256 * 4);
    float* scale  = (float*)alloc(128 * 4);
    float* shift  = (float*)alloc(128 * 4);
    int2*  adj    = (int2*)alloc((size_t)(Ee + Nn) * 8);
    uint*  tmp    = (uint*)alloc((size_t)Nn * 64 * 4);   // bf16-packed h
    float* agg    = (float*)alloc((size_t)Nn * 128 * 4);

    // graph preprocessing
    k_init<<<(Nn + 255) / 256, 256, 0, stream>>>(deg, cursor, colsum);
    k_deg<<<(Ee + 255) / 256, 256, 0, stream>>>(dst, deg);
    k_dinv<<<(Nn + 255) / 256, 256, 0, stream>>>(deg, dinv);
    k_scan1<<<NB_SCAN, 256, 0, stream>>>(deg, bsum);
    k_scan2<<<1, 1, 0, stream>>>(bsum, NB_SCAN);
    k_scan3<<<NB_SCAN, 256, 0, stream>>>(deg, bsum, offs);
    k_fill<<<(Ee + Nn + 255) / 256, 256, 0, stream>>>(src, dst, offs, cursor, dinv, adj);
    // layer 1
    k_gemm<<<GEMM_BLOCKS, 256, 0, stream>>>(x, W1, scale, shift, tmp, 0);
    k_agg<<<AGG_BLOCKS, 256, 0, stream>>>(tmp, offs, adj, b1, agg, colsum);
    k_bnfinal<<<1, 128, 0, stream>>>(colsum, g1, be1, scale, shift);
    // layer 2
    k_gemm<<<GEMM_BLOCKS, 256, 0, stream>>>(agg, W2, scale, shift, tmp, 1);
    k_agg<<<AGG_BLOCKS, 256, 0, stream>>>(tmp, offs, adj, b2, agg, colsum);
    k_bnfinal<<<1, 128, 0, stream>>>(colsum, g2, be2, scale, shift);
    // layer 3
    k_gemm<<<GEMM_BLOCKS, 256, 0, stream>>>(agg, W3, scale, shift, tmp, 1);
    k_agg<<<AGG_BLOCKS, 256, 0, stream>>>(tmp, offs, adj, b3, agg, colsum);
    k_bnfinal<<<1, 128, 0, stream>>>(colsum, g3, be3, scale, shift);
    // pool + linear
    k_pool<<<(Gg * 64 + 255) / 256, 256, 0, stream>>>(agg, bat, scale, shift, Wl, bl, out);
}

// Round 3
// 623.361 us; speedup vs baseline: 2.0196x; 1.2056x over previous
//
#include <hip/hip_runtime.h>
#include <hip/hip_bf16.h>

#define Nn 100000
#define Ee 1600000
#define Hh 128
#define Gg 1000
#define EPSb 1e-5f

#define SCAN_CHUNK 1024
#define NB_SCAN 98          // ceil(100000/1024)
#define AGG_BLOCKS 2048
#define GEMM_BLOCKS 782     // ceil(100000/128)

typedef unsigned int uint;
typedef short short8 __attribute__((ext_vector_type(8)));
typedef float floatx4 __attribute__((ext_vector_type(4)));

// round-to-nearest-even f32 -> bf16 (as low 16 bits of return)
static __device__ __forceinline__ uint bf16rne(float f) {
    uint u = __float_as_uint(f);
    return (u + 0x7fffu + ((u >> 16) & 1u)) >> 16;
}
static __device__ __forceinline__ float bflo(uint u) { return __uint_as_float(u << 16); }
static __device__ __forceinline__ float bfhi(uint u) { return __uint_as_float(u & 0xffff0000u); }

// ---------------- graph preprocessing ----------------

__global__ void k_init(int* __restrict__ deg, int* __restrict__ cursor,
                       float* __restrict__ colsum) {
    int i = blockIdx.x * blockDim.x + threadIdx.x;
    if (i < Nn) { deg[i] = 1; cursor[i] = 0; }
    if (i < 256) colsum[i] = 0.f;
}

__global__ void k_deg(const int* __restrict__ dst, int* __restrict__ deg) {
    int i = blockIdx.x * blockDim.x + threadIdx.x;
    if (i < Ee) atomicAdd(&deg[dst[i]], 1);
}

__global__ void k_dinv(const int* __restrict__ deg, float* __restrict__ dinv) {
    int i = blockIdx.x * blockDim.x + threadIdx.x;
    if (i < Nn) dinv[i] = rsqrtf((float)deg[i]);
}

__global__ void k_scan1(const int* __restrict__ deg, int* __restrict__ bsum) {
    __shared__ int ls[256];
    int t = threadIdx.x;
    int base = blockIdx.x * SCAN_CHUNK + t * 4;
    int s = 0;
#pragma unroll
    for (int j = 0; j < 4; ++j) { int i = base + j; if (i < Nn) s += deg[i]; }
    ls[t] = s;
    __syncthreads();
    for (int off = 128; off; off >>= 1) {
        if (t < off) ls[t] += ls[t + off];
        __syncthreads();
    }
    if (t == 0) bsum[blockIdx.x] = ls[0];
}

__global__ void k_scan2(int* __restrict__ bsum, int nb) {
    int acc = 0;
    for (int b = 0; b < nb; ++b) { int v = bsum[b]; bsum[b] = acc; acc += v; }
}

__global__ void k_scan3(const int* __restrict__ deg, const int* __restrict__ bsum,
                        int* __restrict__ offs) {
    __shared__ int ls[256];
    int t = threadIdx.x;
    int base = blockIdx.x * SCAN_CHUNK + t * 4;
    int d[4]; int s = 0;
#pragma unroll
    for (int j = 0; j < 4; ++j) {
        int i = base + j;
        d[j] = (i < Nn) ? deg[i] : 0;
        s += d[j];
    }
    ls[t] = s;
    __syncthreads();
    for (int off = 1; off < 256; off <<= 1) {
        int u = (t >= off) ? ls[t - off] : 0;
        __syncthreads();
        ls[t] += u;
        __syncthreads();
    }
    int run = bsum[blockIdx.x] + ls[t] - s;   // exclusive prefix for this thread
#pragma unroll
    for (int j = 0; j < 4; ++j) {
        int i = base + j;
        if (i < Nn) offs[i] = run;
        run += d[j];
    }
    if (blockIdx.x == 0 && t == 0) offs[Nn] = Ee + Nn;
}

__global__ void k_fill(const int* __restrict__ src, const int* __restrict__ dst,
                       const int* __restrict__ offs, int* __restrict__ cursor,
                       const float* __restrict__ dinv,
                       int2* __restrict__ adj) {
    int i = blockIdx.x * blockDim.x + threadIdx.x;
    if (i >= Ee + Nn) return;
    int s, d;
    if (i < Ee) { s = src[i]; d = dst[i]; }
    else        { s = d = i - Ee; }
    int pos = offs[d] + atomicAdd(&cursor[d], 1);
    adj[pos] = make_int2(s, __float_as_int(dinv[s] * dinv[d]));
}

// ------------- W conversion: Wtp[n][k/2] = packed bf16 of W[k][n],W[k+1][n] ----

__global__ void k_wconv(const float* __restrict__ W, uint* __restrict__ Wtp) {
    int idx = blockIdx.x * blockDim.x + threadIdx.x;   // 8192
    if (idx >= 128 * 64) return;
    int n = idx >> 6, ku = idx & 63;
    uint lo = bf16rne(W[(size_t)(2 * ku) * 128 + n]);
    uint hi = bf16rne(W[(size_t)(2 * ku + 1) * 128 + n]);
    Wtp[(size_t)n * 64 + ku] = lo | (hi << 16);
}

// ---------------- MFMA GEMM: tmp(bf16) = act(in) @ W ----------------------
// mode 0: in = fp32 x, identity activation.  mode 1: in = packed-bf16 agg,
// activation = relu(v*scale+shift).
// LDS tiles (XT: activations [row=node][k], WT: W^T [row=featOut][k]) are
// bf16-packed uints, 64/row (256B), 16B-granule XOR-swizzled by (row&7) so
// ds_read_b128 fragment loads are <=2-way bank conflicted (free).

__global__ __launch_bounds__(256) void k_gemm(
    const float* __restrict__ inf, const uint* __restrict__ inb,
    const uint* __restrict__ Wtp,
    const float* __restrict__ scale, const float* __restrict__ shift,
    uint* __restrict__ outb, int mode) {
    __shared__ uint XT[128][64];
    __shared__ uint WT[128][64];
    int t = threadIdx.x;
    int rowBase = blockIdx.x * 128;
    int r = t >> 1, half = t & 1;

    {   // stage activations
        int gr = rowBase + r;
        int grc = gr < Nn ? gr : Nn - 1;
        if (mode == 0) {
            const float* sp = inf + (size_t)grc * 128 + half * 64;
#pragma unroll
            for (int q = 0; q < 8; ++q) {
                float4 v0 = *(const float4*)(sp + q * 8);
                float4 v1 = *(const float4*)(sp + q * 8 + 4);
                uint4 o;
                o.x = bf16rne(v0.x) | (bf16rne(v0.y) << 16);
                o.y = bf16rne(v0.z) | (bf16rne(v0.w) << 16);
                o.z = bf16rne(v1.x) | (bf16rne(v1.y) << 16);
                o.w = bf16rne(v1.z) | (bf16rne(v1.w) << 16);
                int g = half * 8 + q;
                *(uint4*)&XT[r][(g ^ (r & 7)) << 2] = o;
            }
        } else {
            const uint* sp = inb + (size_t)grc * 64 + half * 32;
#pragma unroll
            for (int q = 0; q < 8; ++q) {
                uint4 v = *(const uint4*)(sp + q * 4);
                int fb = half * 64 + q * 8;
                float4 s0 = *(const float4*)(scale + fb);
                float4 s1 = *(const float4*)(scale + fb + 4);
                float4 h0 = *(const float4*)(shift + fb);
                float4 h1 = *(const float4*)(shift + fb + 4);
                float a0 = fmaxf(fmaf(bflo(v.x), s0.x, h0.x), 0.f);
                float a1 = fmaxf(fmaf(bfhi(v.x), s0.y, h0.y), 0.f);
                float a2 = fmaxf(fmaf(bflo(v.y), s0.z, h0.z), 0.f);
                float a3 = fmaxf(fmaf(bfhi(v.y), s0.w, h0.w), 0.f);
                float a4 = fmaxf(fmaf(bflo(v.z), s1.x, h1.x), 0.f);
                float a5 = fmaxf(fmaf(bfhi(v.z), s1.y, h1.y), 0.f);
                float a6 = fmaxf(fmaf(bflo(v.w), s1.z, h1.z), 0.f);
                float a7 = fmaxf(fmaf(bfhi(v.w), s1.w, h1.w), 0.f);
                uint4 o;
                o.x = bf16rne(a0) | (bf16rne(a1) << 16);
                o.y = bf16rne(a2) | (bf16rne(a3) << 16);
                o.z = bf16rne(a4) | (bf16rne(a5) << 16);
                o.w = bf16rne(a6) | (bf16rne(a7) << 16);
                int g = half * 8 + q;
                *(uint4*)&XT[r][(g ^ (r & 7)) << 2] = o;
            }
        }
    }
    {   // stage W^T (already packed bf16)
        const uint* sp = Wtp + (size_t)r * 64 + half * 32;
#pragma unroll
        for (int q = 0; q < 8; ++q) {
            uint4 v = *(const uint4*)(sp + q * 4);
            int g = half * 8 + q;
            *(uint4*)&WT[r][(g ^ (r & 7)) << 2] = v;
        }
    }
    __syncthreads();

    int l = t & 63, w = t >> 6;
    int nb = (w >> 1) * 64;       // node-tile base
    int fb2 = (w & 1) * 64;       // feature-tile base
    int lr = l & 15, lk = l >> 4;
    floatx4 zero = {0.f, 0.f, 0.f, 0.f};
    floatx4 acc[4][4];
#pragma unroll
    for (int mi = 0; mi < 4; ++mi)
#pragma unroll
        for (int ni = 0; ni < 4; ++ni) acc[mi][ni] = zero;

#pragma unroll
    for (int kc = 0; kc < 4; ++kc) {
        short8 xf[4], wf[4];
        int g = kc * 4 + lk;
#pragma unroll
        for (int mi = 0; mi < 4; ++mi) {
            int rr = nb + mi * 16 + lr;
            xf[mi] = *(const short8*)&XT[rr][(g ^ (rr & 7)) << 2];
        }
#pragma unroll
        for (int ni = 0; ni < 4; ++ni) {
            int rr = fb2 + ni * 16 + lr;
            wf[ni] = *(const short8*)&WT[rr][(g ^ (rr & 7)) << 2];
        }
#pragma unroll
        for (int mi = 0; mi < 4; ++mi)
#pragma unroll
            for (int ni = 0; ni < 4; ++ni)
                acc[mi][ni] = __builtin_amdgcn_mfma_f32_16x16x32_bf16(
                    wf[ni], xf[mi], acc[mi][ni], 0, 0, 0);
    }

    // epilogue: D col(lane&15)=node, row((lane>>4)*4+reg)=feature
#pragma unroll
    for (int mi = 0; mi < 4; ++mi) {
        int node = rowBase + nb + mi * 16 + lr;
        if (node < Nn) {
            uint* op = outb + (size_t)node * 64;
#pragma unroll
            for (int ni = 0; ni < 4; ++ni) {
                int fo = fb2 + ni * 16 + lk * 4;
                uint2 o;
                o.x = bf16rne(acc[mi][ni][0]) | (bf16rne(acc[mi][ni][1]) << 16);
                o.y = bf16rne(acc[mi][ni][2]) | (bf16rne(acc[mi][ni][3]) << 16);
                *(uint2*)(op + (fo >> 1)) = o;
            }
        }
    }
}

// ------- aggregation: agg[d] = sum_e w*h[src] + bias; BN partials -------
// h is bf16-packed: row stride 64 uints; agg also written bf16-packed.

__global__ __launch_bounds__(256) void k_agg(
    const uint* __restrict__ h32, const int* __restrict__ offs,
    const int2* __restrict__ adj,
    const float* __restrict__ bias, uint* __restrict__ agg,
    float* __restrict__ colsum) {
    __shared__ float ls[256];
    int tid = threadIdx.x;
    ls[tid] = 0.f;
    __syncthreads();
    int lane = tid & 63;
    int gw = blockIdx.x * 4 + (tid >> 6);
    int nw = gridDim.x * 4;
    int c0 = lane * 2;
    float b0 = bias[c0], b1 = bias[c0 + 1];
    float ps0 = 0.f, pq0 = 0.f, ps1 = 0.f, pq1 = 0.f;
    for (int d = gw; d < Nn; d += nw) {
        int beg = offs[d], end = offs[d + 1];
        float a0 = 0.f, a1 = 0.f;
        int i = beg;
        for (; i + 8 <= end; i += 8) {
            int2 e[8];
#pragma unroll
            for (int j = 0; j < 8; ++j) e[j] = adj[i + j];
            uint hv[8];
#pragma unroll
            for (int j = 0; j < 8; ++j)
                hv[j] = h32[(size_t)e[j].x * 64 + lane];
#pragma unroll
            for (int j = 0; j < 8; ++j) {
                float w = __int_as_float(e[j].y);
                a0 = fmaf(w, bflo(hv[j]), a0);
                a1 = fmaf(w, bfhi(hv[j]), a1);
            }
        }
        for (; i < end; ++i) {
            int2 e = adj[i];
            uint hv = h32[(size_t)e.x * 64 + lane];
            float w = __int_as_float(e.y);
            a0 = fmaf(w, bflo(hv), a0);
            a1 = fmaf(w, bfhi(hv), a1);
        }
        a0 += b0; a1 += b1;
        agg[(size_t)d * 64 + lane] = bf16rne(a0) | (bf16rne(a1) << 16);
        ps0 += a0; pq0 += a0 * a0;
        ps1 += a1; pq1 += a1 * a1;
    }
    atomicAdd(&ls[c0], ps0);
    atomicAdd(&ls[c0 + 1], ps1);
    atomicAdd(&ls[128 + c0], pq0);
    atomicAdd(&ls[128 + c0 + 1], pq1);
    __syncthreads();
    atomicAdd(&colsum[tid], ls[tid]);
}

// ---------------- BN finalize: scale/shift, re-zero accumulators ----------

__global__ void k_bnfinal(float* __restrict__ colsum,
                          const float* __restrict__ g, const float* __restrict__ be,
                          float* __restrict__ scale, float* __restrict__ shift) {
    int t = threadIdx.x;  // 128
    float s = colsum[t], q = colsum[128 + t];
    float m = s * (1.0f / Nn);
    float var = q * (1.0f / Nn) - m * m;
    float istd = rsqrtf(var + EPSb);
    float sc = istd * g[t];
    scale[t] = sc;
    shift[t] = fmaf(-m, sc, be[t]);
    colsum[t] = 0.f;
    colsum[128 + t] = 0.f;
}

// ---------------- pool + linear ------------------------------------------

__global__ __launch_bounds__(256) void k_pool(
    const uint* __restrict__ agg, const int* __restrict__ batch,
    const float* __restrict__ scale, const float* __restrict__ shift,
    const float* __restrict__ Wl, const float* __restrict__ bl,
    float* __restrict__ out) {
    int lane = threadIdx.x & 63;
    int g = (blockIdx.x * blockDim.x + threadIdx.x) >> 6;
    if (g >= Gg) return;
    int lo = 0, hi = Nn;
    while (lo < hi) { int mid = (lo + hi) >> 1; if (batch[mid] < g) lo = mid + 1; else hi = mid; }
    int beg = lo;
    hi = Nn;
    while (lo < hi) { int mid = (lo + hi) >> 1; if (batch[mid] < g + 1) lo = mid + 1; else hi = mid; }
    int end = lo;
    int c0 = lane * 2;
    float sc0 = scale[c0], sh0 = shift[c0];
    float sc1 = scale[c0 + 1], sh1 = shift[c0 + 1];
    float s0 = 0.f, s1 = 0.f;
    for (int n = beg; n < end; ++n) {
        uint v = agg[(size_t)n * 64 + lane];
        s0 += fmaxf(fmaf(bflo(v), sc0, sh0), 0.f);
        s1 += fmaxf(fmaf(bfhi(v), sc1, sh1), 0.f);
    }
    float inv = 1.0f / fmaxf((float)(end - beg), 1.0f);
    float part = (s0 * inv) * Wl[c0] + (s1 * inv) * Wl[c0 + 1];
#pragma unroll
    for (int off = 32; off; off >>= 1) part += __shfl_down(part, off);
    if (lane == 0) out[g] = part + bl[0];
}

// ---------------- launch --------------------------------------------------

extern "C" void kernel_launch(void* const* d_in, const int* in_sizes, int n_in,
                              void* d_out, int out_size, void* d_ws, size_t ws_size,
                              hipStream_t stream) {
    const float* x   = (const float*)d_in[0];
    const int*   ei  = (const int*)d_in[1];
    const int*   src = ei;
    const int*   dst = ei + Ee;
    const int*   bat = (const int*)d_in[2];
    const float* W1 = (const float*)d_in[3];
    const float* b1 = (const float*)d_in[4];
    const float* g1 = (const float*)d_in[5];
    const float* be1 = (const float*)d_in[6];
    const float* W2 = (const float*)d_in[7];
    const float* b2 = (const float*)d_in[8];
    const float* g2 = (const float*)d_in[9];
    const float* be2 = (const float*)d_in[10];
    const float* W3 = (const float*)d_in[11];
    const float* b3 = (const float*)d_in[12];
    const float* g3 = (const float*)d_in[13];
    const float* be3 = (const float*)d_in[14];
    const float* Wl = (const float*)d_in[15];
    const float* bl = (const float*)d_in[16];
    float* out = (float*)d_out;

    char* w = (char*)d_ws;
    auto alloc = [&](size_t bytes) {
        void* p = (void*)w;
        w += (bytes + 255) & ~(size_t)255;
        return p;
    };
    int*   deg    = (int*)alloc((size_t)Nn * 4);
    int*   cursor = (int*)alloc((size_t)Nn * 4);
    int*   offs   = (int*)alloc((size_t)(Nn + 1) * 4);
    int*   bsum   = (int*)alloc(256 * 4);
    float* dinv   = (float*)alloc((size_t)Nn * 4);
    float* colsum = (float*)alloc(256 * 4);
    float* scale  = (float*)alloc(128 * 4);
    float* shift  = (float*)alloc(128 * 4);
    uint*  Wt1    = (uint*)alloc(128 * 64 * 4);
    uint*  Wt2    = (uint*)alloc(128 * 64 * 4);
    uint*  Wt3    = (uint*)alloc(128 * 64 * 4);
    int2*  adj    = (int2*)alloc((size_t)(Ee + Nn) * 8);
    uint*  tmp    = (uint*)alloc((size_t)Nn * 64 * 4);   // bf16-packed h
    uint*  agg    = (uint*)alloc((size_t)Nn * 64 * 4);   // bf16-packed agg

    // graph preprocessing + weight conversion
    k_init<<<(Nn + 255) / 256, 256, 0, stream>>>(deg, cursor, colsum);
    k_deg<<<(Ee + 255) / 256, 256, 0, stream>>>(dst, deg);
    k_dinv<<<(Nn + 255) / 256, 256, 0, stream>>>(deg, dinv);
    k_scan1<<<NB_SCAN, 256, 0, stream>>>(deg, bsum);
    k_scan2<<<1, 1, 0, stream>>>(bsum, NB_SCAN);
    k_scan3<<<NB_SCAN, 256, 0, stream>>>(deg, bsum, offs);
    k_fill<<<(Ee + Nn + 255) / 256, 256, 0, stream>>>(src, dst, offs, cursor, dinv, adj);
    k_wconv<<<32, 256, 0, stream>>>(W1, Wt1);
    k_wconv<<<32, 256, 0, stream>>>(W2, Wt2);
    k_wconv<<<32, 256, 0, stream>>>(W3, Wt3);
    // layer 1
    k_gemm<<<GEMM_BLOCKS, 256, 0, stream>>>(x, (const uint*)0, Wt1, scale, shift, tmp, 0);
    k_agg<<<AGG_BLOCKS, 256, 0, stream>>>(tmp, offs, adj, b1, agg, colsum);
    k_bnfinal<<<1, 128, 0, stream>>>(colsum, g1, be1, scale, shift);
    // layer 2
    k_gemm<<<GEMM_BLOCKS, 256, 0, stream>>>((const float*)0, agg, Wt2, scale, shift, tmp, 1);
    k_agg<<<AGG_BLOCKS, 256, 0, stream>>>(tmp, offs, adj, b2, agg, colsum);
    k_bnfinal<<<1, 128, 0, stream>>>(colsum, g2, be2, scale, shift);
    // layer 3
    k_gemm<<<GEMM_BLOCKS, 256, 0, stream>>>((const float*)0, agg, Wt3, scale, shift, tmp, 1);
    k_agg<<<AGG_BLOCKS, 256, 0, stream>>>(tmp, offs, adj, b3, agg, colsum);
    k_bnfinal<<<1, 128, 0, stream>>>(colsum, g3, be3, scale, shift);
    // pool + linear
    k_pool<<<(Gg * 64 + 255) / 256, 256, 0, stream>>>(agg, bat, scale, shift, Wl, bl, out);
}